// Round 18
// baseline (619.453 us; speedup 1.0000x reference)
//
#include <hip/hip_runtime.h>
#include <hip/hip_fp16.h>

#define N_NODES 100000
#define N_EDGES 3200000
#define N_GRAPHS 256
#define HID 64

// atomic-free bucketed CSR build — 512 nodes/bucket, write-contiguity optimized
#define BSHIFT 9                 // 512 nodes per bucket
#define NPB 512                  // nodes per bucket
#define NBUCK 196                // ceil(100000/512)
#define PCHUNK 8192              // edges per partition block (~42 entries/bucket/block)
#define NPBLK 391                // ceil(3200000/8192)

// pass A: per-block private LDS histogram; hist layout [block][bucket] (coalesced)
__global__ __launch_bounds__(256) void k_hist(
        const int* __restrict__ dst, int* __restrict__ hist) {
    __shared__ int h[NBUCK];
    int t = threadIdx.x;
    for (int j = t; j < NBUCK; j += 256) h[j] = 0;
    __syncthreads();
    int base = blockIdx.x * PCHUNK;
    int end = min(base + PCHUNK, N_EDGES);
    for (int i = base + t; i < end; i += 256)
        atomicAdd(&h[dst[i] >> BSHIFT], 1);
    __syncthreads();
    for (int j = t; j < NBUCK; j += 256)
        hist[(size_t)blockIdx.x * NBUCK + j] = h[j];
}

// pass B1: per-bucket exclusive scan over NPBLK block counts (NPBLK=391 <= 512)
__global__ __launch_bounds__(512) void k_scan_rows(
        int* __restrict__ hist, int* __restrict__ btotal) {
    __shared__ int s[512];
    int b = blockIdx.x, t = threadIdx.x;
    int v = (t < NPBLK) ? hist[(size_t)t * NBUCK + b] : 0;
    s[t] = v;
    __syncthreads();
    for (int off = 1; off < 512; off <<= 1) {
        int add = (t >= off) ? s[t - off] : 0;
        __syncthreads();
        s[t] += add;
        __syncthreads();
    }
    if (t < NPBLK) hist[(size_t)t * NBUCK + b] = s[t] - v;  // exclusive
    if (t == 511) btotal[b] = s[511];
}

// pass B2: exclusive scan over NBUCK bucket totals (single block)
__global__ __launch_bounds__(256) void k_scan_base(
        const int* __restrict__ btotal, int* __restrict__ bbase,
        int* __restrict__ rowp_last) {
    __shared__ int s[256];
    int t = threadIdx.x;
    int v = (t < NBUCK) ? btotal[t] : 0;
    s[t] = v;
    __syncthreads();
    for (int off = 1; off < 256; off <<= 1) {
        int add = (t >= off) ? s[t - off] : 0;
        __syncthreads();
        s[t] += add;
        __syncthreads();
    }
    if (t < NBUCK) bbase[t] = s[t] - v;
    if (t == NBUCK - 1) rowp_last[0] = s[t];
}

// pass C: scatter packed pairs (src | (d&511)<<17) using exact per-(block,bucket)
// offsets (LDS cursors). ~42 consecutive entries per bucket per block.
__global__ __launch_bounds__(256) void k_scatter(
        const int* __restrict__ src, const int* __restrict__ dst,
        const int* __restrict__ hist, const int* __restrict__ bbase,
        unsigned* __restrict__ pairs) {
    __shared__ int cur[NBUCK];
    int t = threadIdx.x;
    for (int j = t; j < NBUCK; j += 256)
        cur[j] = bbase[j] + hist[(size_t)blockIdx.x * NBUCK + j];
    __syncthreads();
    int base = blockIdx.x * PCHUNK;
    int end = min(base + PCHUNK, N_EDGES);
    for (int i = base + t; i < end; i += 256) {
        int d = dst[i], s = src[i];
        int b = d >> BSHIFT;
        int pos = atomicAdd(&cur[b], 1);
        pairs[pos] = (unsigned)s | ((unsigned)(d & (NPB - 1)) << 17);
    }
}

// pass D: per-bucket two-pass counting sort, no staging buffer
__global__ __launch_bounds__(512) void k_sort(
        const unsigned* __restrict__ pairs, const int* __restrict__ btotal,
        const int* __restrict__ bbase, int* __restrict__ esrc,
        int* __restrict__ rowp, float* __restrict__ dinv) {
    __shared__ int lcnt[NPB];
    __shared__ int lscan[NPB];
    __shared__ int lcur[NPB];
    int b = blockIdx.x, t = threadIdx.x;
    int nb = btotal[b];
    int base = bbase[b];
    lcnt[t] = 0;
    __syncthreads();
    for (int i = t; i < nb; i += 512) atomicAdd(&lcnt[pairs[base + i] >> 17], 1);
    __syncthreads();
    lscan[t] = lcnt[t];
    __syncthreads();
    for (int off = 1; off < NPB; off <<= 1) {
        int add = (t >= off) ? lscan[t - off] : 0;
        __syncthreads();
        lscan[t] += add;
        __syncthreads();
    }
    lcur[t] = lscan[t] - lcnt[t];
    __syncthreads();
    for (int i = t; i < nb; i += 512) {
        unsigned u = pairs[base + i];
        int d = u >> 17;
        int p = atomicAdd(&lcur[d], 1);
        esrc[base + p] = (int)(u & 0x1FFFFu);
    }
    int node = b * NPB + t;
    if (node < N_NODES) {
        rowp[node] = base + lscan[t] - lcnt[t];
        dinv[node] = rsqrtf((float)lcnt[t] + 1.0f);  // in-degree + self-loop
    }
}

// ---------------- weight folding ----------------
//   Wpack[64][96] = [W3@Wm1 | W3@Wp1],  bpack[96] = [b3@Wm1+bm1 | b3@Wp1+bp1]
//   Wcg[64][64]   = W3@Wg,              bcg[64]   = b3@Wg + bg
__global__ __launch_bounds__(256) void k_fold(
        const float* __restrict__ W3, const float* __restrict__ b3,
        const float* __restrict__ Wm1, const float* __restrict__ bm1,
        const float* __restrict__ Wp1, const float* __restrict__ bp1,
        const float* __restrict__ Wg, const float* __restrict__ bg,
        float* __restrict__ Wpack, float* __restrict__ bpack,
        float* __restrict__ Wcg, float* __restrict__ bcg) {
    int tid = blockIdx.x * 256 + threadIdx.x;
    if (tid < 6144) {                       // Wpack
        int k = tid / 96, c = tid % 96;
        float s = 0.f;
        if (c < 64) {
#pragma unroll 16
            for (int j = 0; j < 64; ++j) s += W3[k * 64 + j] * Wm1[j * 64 + c];
        } else {
            int cc = c - 64;
#pragma unroll 16
            for (int j = 0; j < 64; ++j) s += W3[k * 64 + j] * Wp1[j * 32 + cc];
        }
        Wpack[tid] = s;
    } else if (tid < 10240) {               // Wcg
        int t2 = tid - 6144;
        int k = t2 / 64, c = t2 % 64;
        float s = 0.f;
#pragma unroll 16
        for (int j = 0; j < 64; ++j) s += W3[k * 64 + j] * Wg[j * 64 + c];
        Wcg[t2] = s;
    } else if (tid < 10336) {               // bpack
        int c = tid - 10240;
        float s;
        if (c < 64) {
            s = bm1[c];
            for (int j = 0; j < 64; ++j) s += b3[j] * Wm1[j * 64 + c];
        } else {
            int cc = c - 64;
            s = bp1[cc];
            for (int j = 0; j < 64; ++j) s += b3[j] * Wp1[j * 32 + cc];
        }
        bpack[c] = s;
    } else if (tid < 10400) {               // bcg
        int c = tid - 10336;
        float s = bg[c];
        for (int j = 0; j < 64; ++j) s += b3[j] * Wg[j * 64 + c];
        bcg[c] = s;
    }
}

// ---------------- prepack: xsh[n][k] = fp16(x[n][k] * dinv[n]) ----------------
__global__ __launch_bounds__(256) void k_prepack(
        const float* __restrict__ x, const float* __restrict__ dinv,
        __half* __restrict__ xsh) {
    int n = blockIdx.x * 256 + threadIdx.x;
    if (n >= N_NODES) return;
    float dv = dinv[n];
    const float4* xr = (const float4*)(x + (size_t)n * 8);
    float4 a = xr[0], b = xr[1];
    __half2 h0 = __halves2half2(__float2half_rn(a.x * dv), __float2half_rn(a.y * dv));
    __half2 h1 = __halves2half2(__float2half_rn(a.z * dv), __float2half_rn(a.w * dv));
    __half2 h2 = __halves2half2(__float2half_rn(b.x * dv), __float2half_rn(b.y * dv));
    __half2 h3 = __halves2half2(__float2half_rn(b.z * dv), __float2half_rn(b.w * dv));
    __half2* o = (__half2*)(xsh + (size_t)n * 8);
    o[0] = h0; o[1] = h1; o[2] = h2; o[3] = h3;
}

// ---------------- fused layer 1: agg8 (fp16 prescaled) + transform 8->64 ----------
__global__ __launch_bounds__(256) void k_agg8t(
        const __half* __restrict__ xsh, const float* __restrict__ dinv,
        const int* __restrict__ rp, const int* __restrict__ esrc,
        const float* __restrict__ W1, const float* __restrict__ b1,
        __half* __restrict__ Bout) {
    int gid = (blockIdx.x * 256 + threadIdx.x) >> 5;  // node
    int l = threadIdx.x & 31;
    if (gid >= N_NODES) return;
    int beg = rp[gid], end = rp[gid + 1];
    float a[8];
#pragma unroll
    for (int i = 0; i < 8; ++i) a[i] = 0.f;
    for (int e = beg + l; e < end; e += 32) {
        int s = esrc[e];
        uint4 v = *(const uint4*)(xsh + (size_t)s * 8);
        const __half2* h = (const __half2*)&v;
#pragma unroll
        for (int i = 0; i < 4; ++i) {
            float2 f = __half22float2(h[i]);
            a[2 * i] += f.x; a[2 * i + 1] += f.y;
        }
    }
#pragma unroll
    for (int off = 1; off < 32; off <<= 1) {
#pragma unroll
        for (int i = 0; i < 8; ++i) a[i] += __shfl_xor(a[i], off);
    }
    float dvw = dinv[gid];
    uint4 sv = *(const uint4*)(xsh + (size_t)gid * 8);
    const __half2* sh = (const __half2*)&sv;
    float y[8];
#pragma unroll
    for (int i = 0; i < 4; ++i) {
        float2 fs = __half22float2(sh[i]);
        y[2 * i]     = dvw * (a[2 * i] + fs.x);
        y[2 * i + 1] = dvw * (a[2 * i + 1] + fs.y);
    }
    float acc0 = b1[l], acc1 = b1[l + 32];
#pragma unroll
    for (int k = 0; k < 8; ++k) {
        acc0 += y[k] * W1[k * 64 + l];
        acc1 += y[k] * W1[k * 64 + l + 32];
    }
    Bout[(size_t)gid * 64 + l]      = __float2half_rn(fmaxf(acc0, 0.f) * dvw);
    Bout[(size_t)gid * 64 + l + 32] = __float2half_rn(fmaxf(acc1, 0.f) * dvw);
}

// ---------------- 64-feature aggregate, fp16 operand, 8-slot wide-load form ----------
__global__ __launch_bounds__(256) void k_agg64h(
        const __half* __restrict__ B, float* __restrict__ Y,
        const float* __restrict__ dinv, const int* __restrict__ rp,
        const int* __restrict__ esrc) {
    int wid = (blockIdx.x * 256 + threadIdx.x) >> 6;
    int lane = threadIdx.x & 63;
    if (wid >= N_NODES) return;
    int beg = rp[wid], end = rp[wid + 1];
    int g = lane >> 3;          // edge slot 0..7
    int fl = (lane & 7) << 3;   // half-index base (8 halfs per lane)
    float a0[8], a1[8];
#pragma unroll
    for (int i = 0; i < 8; ++i) { a0[i] = 0.f; a1[i] = 0.f; }
    int e = beg + g;
    for (; e + 8 < end; e += 16) {
        int s0 = esrc[e];
        int s1 = esrc[e + 8];
        uint4 v0 = *(const uint4*)(B + (size_t)s0 * 64 + fl);
        uint4 v1 = *(const uint4*)(B + (size_t)s1 * 64 + fl);
        const __half2* h0 = (const __half2*)&v0;
        const __half2* h1 = (const __half2*)&v1;
#pragma unroll
        for (int i = 0; i < 4; ++i) {
            float2 f0 = __half22float2(h0[i]);
            float2 f1 = __half22float2(h1[i]);
            a0[2 * i] += f0.x; a0[2 * i + 1] += f0.y;
            a1[2 * i] += f1.x; a1[2 * i + 1] += f1.y;
        }
    }
    if (e < end) {
        int s0 = esrc[e];
        uint4 v0 = *(const uint4*)(B + (size_t)s0 * 64 + fl);
        const __half2* h0 = (const __half2*)&v0;
#pragma unroll
        for (int i = 0; i < 4; ++i) {
            float2 f0 = __half22float2(h0[i]);
            a0[2 * i] += f0.x; a0[2 * i + 1] += f0.y;
        }
    }
#pragma unroll
    for (int i = 0; i < 8; ++i) a0[i] += a1[i];
#pragma unroll
    for (int off = 8; off <= 32; off <<= 1) {
#pragma unroll
        for (int i = 0; i < 8; ++i) a0[i] += __shfl_xor(a0[i], off);
    }
    if (lane < 8) {
        uint4 sv = *(const uint4*)(B + (size_t)wid * 64 + fl);
        const __half2* sh = (const __half2*)&sv;
        float dv = dinv[wid];
        float r[8];
#pragma unroll
        for (int i = 0; i < 4; ++i) {
            float2 fs = __half22float2(sh[i]);
            r[2 * i]     = dv * (a0[2 * i] + fs.x);
            r[2 * i + 1] = dv * (a0[2 * i + 1] + fs.y);
        }
        float4 w0 = {r[0], r[1], r[2], r[3]};
        float4 w1 = {r[4], r[5], r[6], r[7]};
        float* yo = Y + (size_t)wid * 64 + fl;
        *(float4*)(yo) = w0;
        *(float4*)(yo + 4) = w1;
    }
}

// register-tiled GEMM (round-14 form, LDS-staged): out = relu(A@W + b)*dinv, fp16 out
__global__ __launch_bounds__(256) void k_gemm64(
        const float* __restrict__ A, const float* __restrict__ W,
        const float* __restrict__ bias, const float* __restrict__ dinv,
        __half* __restrict__ out16) {
    __shared__ float Al[128 * 64];
    __shared__ float Wl[64 * 64];
    int tid = threadIdx.x;
    int base = blockIdx.x * 128;

    for (int idx = tid; idx < 128 * 16; idx += 256) {
        int r = idx >> 4, c4 = idx & 15;
        float4 v = {0.f, 0.f, 0.f, 0.f};
        if (base + r < N_NODES)
            v = *(const float4*)(A + (size_t)(base + r) * 64 + c4 * 4);
        *(float4*)(Al + r * 64 + c4 * 4) = v;
    }
    for (int idx = tid; idx < 64 * 16; idx += 256) {
        int r = idx >> 4, c4 = idx & 15;
        *(float4*)(Wl + r * 64 + c4 * 4) = *(const float4*)(W + r * 64 + c4 * 4);
    }
    __syncthreads();

    int tc = tid & 15;
    int tr = tid >> 4;   // 0..15

    float acc[8][4];
#pragma unroll
    for (int i = 0; i < 8; ++i)
#pragma unroll
        for (int c = 0; c < 4; ++c) acc[i][c] = 0.f;

    for (int kb = 0; kb < 16; ++kb) {
        float w0[4], w1[4], w2[4], w3[4];
        {
            const float* wp = Wl + (kb * 4) * 64 + tc * 4;
            float4 a = *(const float4*)(wp);
            float4 b = *(const float4*)(wp + 64);
            float4 c = *(const float4*)(wp + 128);
            float4 d = *(const float4*)(wp + 192);
            w0[0] = a.x; w0[1] = a.y; w0[2] = a.z; w0[3] = a.w;
            w1[0] = b.x; w1[1] = b.y; w1[2] = b.z; w1[3] = b.w;
            w2[0] = c.x; w2[1] = c.y; w2[2] = c.z; w2[3] = c.w;
            w3[0] = d.x; w3[1] = d.y; w3[2] = d.z; w3[3] = d.w;
        }
#pragma unroll
        for (int i = 0; i < 8; ++i) {
            float4 af = *(const float4*)(Al + (tr * 8 + i) * 64 + kb * 4);
#pragma unroll
            for (int c = 0; c < 4; ++c)
                acc[i][c] += af.x * w0[c] + af.y * w1[c] + af.z * w2[c] + af.w * w3[c];
        }
    }

    float4 bv = *(const float4*)(bias + tc * 4);
#pragma unroll
    for (int i = 0; i < 8; ++i) {
        int r = base + tr * 8 + i;
        if (r < N_NODES) {
            float dv = dinv[r];
            float o0 = fmaxf(acc[i][0] + bv.x, 0.f) * dv;
            float o1 = fmaxf(acc[i][1] + bv.y, 0.f) * dv;
            float o2 = fmaxf(acc[i][2] + bv.z, 0.f) * dv;
            float o3 = fmaxf(acc[i][3] + bv.w, 0.f) * dv;
            __half2 h01 = __halves2half2(__float2half_rn(o0), __float2half_rn(o1));
            __half2 h23 = __halves2half2(__float2half_rn(o2), __float2half_rn(o3));
            __half2* dst = (__half2*)(out16 + (size_t)r * 64 + tc * 4);
            dst[0] = h01; dst[1] = h23;
        }
    }
}

// ---------------- thread-per-node fused head: M, P1 never materialized ----------
// om[j] = bm2[j] + sum_f relu(y.Wpack[:,f]+bpack[f]) * Wm2[f][j]
// op    = bp2    + sum_f relu(y.Wpack[:,64+f]+bpack[64+f]) * Wp2[f]
__global__ __launch_bounds__(256) void k_headreg(
        const float* __restrict__ Y, const float* __restrict__ Wpack,
        const float* __restrict__ bpack,
        const float* __restrict__ Wm2, const float* __restrict__ bm2,
        const float* __restrict__ Wp2, const float* __restrict__ bp2,
        float* __restrict__ out_m, float* __restrict__ out_p) {
    int n = blockIdx.x * 256 + threadIdx.x;
    if (n >= N_NODES) return;
    float y[64];
    const float4* yr = (const float4*)(Y + (size_t)n * 64);
#pragma unroll
    for (int i = 0; i < 16; ++i) {
        float4 v = yr[i];
        y[4 * i] = v.x; y[4 * i + 1] = v.y; y[4 * i + 2] = v.z; y[4 * i + 3] = v.w;
    }
    float om[9];
#pragma unroll
    for (int j = 0; j < 9; ++j) om[j] = bm2[j];
    for (int f = 0; f < 64; ++f) {
        float m = bpack[f];
#pragma unroll 16
        for (int k = 0; k < 64; ++k) m += y[k] * Wpack[k * 96 + f];
        m = fmaxf(m, 0.f);
#pragma unroll
        for (int j = 0; j < 9; ++j) om[j] += m * Wm2[f * 9 + j];
    }
    float op = bp2[0];
    for (int f = 0; f < 32; ++f) {
        float p = bpack[64 + f];
#pragma unroll 16
        for (int k = 0; k < 64; ++k) p += y[k] * Wpack[k * 96 + 64 + f];
        op += fmaxf(p, 0.f) * Wp2[f];
    }
#pragma unroll
    for (int j = 0; j < 9; ++j) out_m[(size_t)n * 9 + j] = om[j];
    out_p[n] = op;
}

// ---------------- fused per-graph head: pool + xglobal + heuristic ----------------
__global__ __launch_bounds__(256) void k_graphhead(
        const float* __restrict__ A, const int* __restrict__ batch,
        const float* __restrict__ Wcg, const float* __restrict__ bcg,
        const float* __restrict__ Wh1, const float* __restrict__ bh1,
        const float* __restrict__ Wh2, const float* __restrict__ bh2,
        float* __restrict__ out_h) {
    __shared__ float l[256];
    __shared__ float xgp[64];
    __shared__ float xg[64];
    int gph = blockIdx.x;
    int t = threadIdx.x;
    int lo = 0, hi = N_NODES;
    int target = (t & 1) ? gph + 1 : gph;
    while (lo < hi) {
        int mid = (lo + hi) >> 1;
        if (batch[mid] < target) lo = mid + 1; else hi = mid;
    }
    __shared__ int bounds[2];
    if (t < 2) bounds[t] = lo;
    __syncthreads();
    int beg = bounds[0], end = bounds[1];

    int lane = t & 63, grp = t >> 6;
    float acc = 0.f;
    for (int r = beg + grp; r < end; r += 4) acc += A[(size_t)r * 64 + lane];
    l[t] = acc;
    __syncthreads();
    if (t < 64) {
        float s = l[t] + l[t + 64] + l[t + 128] + l[t + 192];
        xgp[t] = s / fmaxf((float)(end - beg), 1.f);
    }
    __syncthreads();
    {
        int c = t & 63, q = t >> 6;
        float p = 0.f;
#pragma unroll
        for (int k = 0; k < 16; ++k)
            p += xgp[q * 16 + k] * Wcg[(q * 16 + k) * 64 + c];
        l[t] = p;
        __syncthreads();
        if (t < 64)
            xg[t] = fmaxf(l[t] + l[t + 64] + l[t + 128] + l[t + 192] + bcg[t], 0.f);
    }
    __syncthreads();
    if (t < 32) {
        float hj = bh1[t];
#pragma unroll 16
        for (int k = 0; k < 64; ++k) hj += xg[k] * Wh1[k * 32 + t];
        float q = fmaxf(hj, 0.f) * Wh2[t];
#pragma unroll
        for (int off = 16; off; off >>= 1) q += __shfl_xor(q, off);
        if (t == 0) out_h[gph] = q + bh2[0];
    }
}

// ---------------- launch ----------------

extern "C" void kernel_launch(void* const* d_in, const int* in_sizes, int n_in,
                              void* d_out, int out_size, void* d_ws, size_t ws_size,
                              hipStream_t stream) {
    const float* x    = (const float*)d_in[0];
    const int*   ei   = (const int*)d_in[1];
    const int*   batch= (const int*)d_in[2];
    const float* W1   = (const float*)d_in[3];
    const float* b1   = (const float*)d_in[4];
    const float* W2   = (const float*)d_in[5];
    const float* b2   = (const float*)d_in[6];
    const float* W3   = (const float*)d_in[7];
    const float* b3   = (const float*)d_in[8];
    const float* Wg   = (const float*)d_in[9];
    const float* bg   = (const float*)d_in[10];
    const float* Wh1  = (const float*)d_in[11];
    const float* bh1  = (const float*)d_in[12];
    const float* Wh2  = (const float*)d_in[13];
    const float* bh2  = (const float*)d_in[14];
    const float* Wm1  = (const float*)d_in[15];
    const float* bm1  = (const float*)d_in[16];
    const float* Wm2  = (const float*)d_in[17];
    const float* bm2  = (const float*)d_in[18];
    const float* Wp1  = (const float*)d_in[19];
    const float* bp1  = (const float*)d_in[20];
    const float* Wp2  = (const float*)d_in[21];
    const float* bp2  = (const float*)d_in[22];

    const int* e_src = ei;
    const int* e_dst = ei + N_EDGES;

    char* ws = (char*)d_ws;
    size_t off = 0;
    auto alloc = [&](size_t bytes) {
        void* p = ws + off;
        off += (bytes + 255) & ~(size_t)255;
        return p;
    };
    float* bufA   = (float*)alloc(N_NODES * 64 * sizeof(float));   // 25.6 MB
    float* bufB   = (float*)alloc(N_NODES * 64 * sizeof(float));   // 25.6 MB
    float* dinv   = (float*)alloc(N_NODES * sizeof(float));
    int*   rowp   = (int*)  alloc((N_NODES + 1) * sizeof(int));
    int*   esrc   = (int*)  alloc(N_EDGES * sizeof(int));          // 12.8 MB
    int*   hist   = (int*)  alloc((size_t)NBUCK * NPBLK * sizeof(int)); // 306 KB
    int*   btotal = (int*)  alloc(NBUCK * sizeof(int));
    int*   bbase  = (int*)  alloc(NBUCK * sizeof(int));
    __half* xsh   = (__half*)alloc(N_NODES * 8 * sizeof(__half));  // 1.6 MB
    float* Wpack  = (float*)alloc(64 * 96 * sizeof(float));
    float* bpack  = (float*)alloc(96 * sizeof(float));
    float* Wcg    = (float*)alloc(64 * 64 * sizeof(float));
    float* bcg    = (float*)alloc(64 * sizeof(float));
    // aliases:
    //   pairs (12.8 MB) in bufA[0..) — dead after k_sort, before bufA first written (y2)
    //   B2h (fp16) = bufB[0 .. 3.2M floats); B3h (fp16) = bufB[3.2M .. 6.4M floats)
    //   y2 = bufA (fp32), y3 = bufA (fp32)
    unsigned* pairs = (unsigned*)bufA;
    __half* B2h = (__half*)bufB;
    __half* B3h = (__half*)(bufB + 3200000);
    (void)ws_size; (void)n_in; (void)in_sizes; (void)out_size;

    float* out_h = (float*)d_out;                // [256]
    float* out_m = (float*)d_out + 256;          // [100000*9]
    float* out_p = (float*)d_out + 256 + 900000; // [100000]

    const int TB = 256;
    dim3 blkWave((N_NODES * 64 + TB - 1) / TB);   // one wave per node
    dim3 blkHalf((N_NODES * 32 + TB - 1) / TB);   // 32 lanes per node
    const int NT = 782;                           // ceil(100000/128) GEMM tiles

    // CSR build — atomic-free 3-pass partition + per-bucket two-pass sort
    k_hist<<<NPBLK, TB, 0, stream>>>(e_dst, hist);
    k_scan_rows<<<NBUCK, 512, 0, stream>>>(hist, btotal);
    k_scan_base<<<1, 256, 0, stream>>>(btotal, bbase, rowp + N_NODES);
    k_scatter<<<NPBLK, TB, 0, stream>>>(e_src, e_dst, hist, bbase, pairs);
    k_sort<<<NBUCK, 512, 0, stream>>>(pairs, btotal, bbase, esrc, rowp, dinv);

    // fold W3 into head/global weights (tiny)
    k_fold<<<41, TB, 0, stream>>>(W3, b3, Wm1, bm1, Wp1, bp1, Wg, bg,
                                  Wpack, bpack, Wcg, bcg);

    // layer 1: prepack + fused agg8 + transform -> B2' (fp16)
    k_prepack<<<(N_NODES + TB - 1) / TB, TB, 0, stream>>>(x, dinv, xsh);
    k_agg8t<<<blkHalf, TB, 0, stream>>>(xsh, dinv, rowp, esrc, W1, b1, B2h);
    // layer 2: fp16 gather -> y2 (fp32, bufA); GEMM -> B3' (fp16)
    k_agg64h<<<blkWave, TB, 0, stream>>>(B2h, bufA, dinv, rowp, esrc);
    k_gemm64<<<NT, 256, 0, stream>>>(bufA, W2, b2, dinv, B3h);
    // layer 3: fp16 gather -> y3 (fp32, bufA; y2 dead)
    k_agg64h<<<blkWave, TB, 0, stream>>>(B3h, bufA, dinv, rowp, esrc);

    // node heads: thread-per-node register kernel (M/P1 never materialized)
    k_headreg<<<(N_NODES + TB - 1) / TB, TB, 0, stream>>>(
        bufA, Wpack, bpack, Wm2, bm2, Wp2, bp2, out_m, out_p);

    // fused per-graph head (y3 = bufA, folded Wcg/bcg)
    k_graphhead<<<N_GRAPHS, TB, 0, stream>>>(bufA, batch, Wcg, bcg,
                                             Wh1, bh1, Wh2, bh2, out_h);
}

// Round 19
// 347.143 us; speedup vs baseline: 1.7844x; 1.7844x over previous
//
#include <hip/hip_runtime.h>
#include <hip/hip_fp16.h>

#define N_NODES 100000
#define N_EDGES 3200000
#define N_GRAPHS 256
#define HID 64

// atomic-free bucketed CSR build — 512 nodes/bucket, write-contiguity optimized
#define BSHIFT 9                 // 512 nodes per bucket
#define NPB 512                  // nodes per bucket
#define NBUCK 196                // ceil(100000/512)
#define PCHUNK 8192              // edges per partition block (~42 entries/bucket/block)
#define NPBLK 391                // ceil(3200000/8192)

// pass A: per-block private LDS histogram; hist layout [block][bucket] (coalesced)
__global__ __launch_bounds__(256) void k_hist(
        const int* __restrict__ dst, int* __restrict__ hist) {
    __shared__ int h[NBUCK];
    int t = threadIdx.x;
    for (int j = t; j < NBUCK; j += 256) h[j] = 0;
    __syncthreads();
    int base = blockIdx.x * PCHUNK;
    int end = min(base + PCHUNK, N_EDGES);
    for (int i = base + t; i < end; i += 256)
        atomicAdd(&h[dst[i] >> BSHIFT], 1);
    __syncthreads();
    for (int j = t; j < NBUCK; j += 256)
        hist[(size_t)blockIdx.x * NBUCK + j] = h[j];
}

// pass B1: per-bucket exclusive scan over NPBLK block counts (NPBLK=391 <= 512)
__global__ __launch_bounds__(512) void k_scan_rows(
        int* __restrict__ hist, int* __restrict__ btotal) {
    __shared__ int s[512];
    int b = blockIdx.x, t = threadIdx.x;
    int v = (t < NPBLK) ? hist[(size_t)t * NBUCK + b] : 0;
    s[t] = v;
    __syncthreads();
    for (int off = 1; off < 512; off <<= 1) {
        int add = (t >= off) ? s[t - off] : 0;
        __syncthreads();
        s[t] += add;
        __syncthreads();
    }
    if (t < NPBLK) hist[(size_t)t * NBUCK + b] = s[t] - v;  // exclusive
    if (t == 511) btotal[b] = s[511];
}

// pass B2: exclusive scan over NBUCK bucket totals (single block)
__global__ __launch_bounds__(256) void k_scan_base(
        const int* __restrict__ btotal, int* __restrict__ bbase,
        int* __restrict__ rowp_last) {
    __shared__ int s[256];
    int t = threadIdx.x;
    int v = (t < NBUCK) ? btotal[t] : 0;
    s[t] = v;
    __syncthreads();
    for (int off = 1; off < 256; off <<= 1) {
        int add = (t >= off) ? s[t - off] : 0;
        __syncthreads();
        s[t] += add;
        __syncthreads();
    }
    if (t < NBUCK) bbase[t] = s[t] - v;
    if (t == NBUCK - 1) rowp_last[0] = s[t];
}

// pass C: scatter packed pairs (src | (d&511)<<17) using exact per-(block,bucket)
// offsets (LDS cursors). ~42 consecutive entries per bucket per block.
__global__ __launch_bounds__(256) void k_scatter(
        const int* __restrict__ src, const int* __restrict__ dst,
        const int* __restrict__ hist, const int* __restrict__ bbase,
        unsigned* __restrict__ pairs) {
    __shared__ int cur[NBUCK];
    int t = threadIdx.x;
    for (int j = t; j < NBUCK; j += 256)
        cur[j] = bbase[j] + hist[(size_t)blockIdx.x * NBUCK + j];
    __syncthreads();
    int base = blockIdx.x * PCHUNK;
    int end = min(base + PCHUNK, N_EDGES);
    for (int i = base + t; i < end; i += 256) {
        int d = dst[i], s = src[i];
        int b = d >> BSHIFT;
        int pos = atomicAdd(&cur[b], 1);
        pairs[pos] = (unsigned)s | ((unsigned)(d & (NPB - 1)) << 17);
    }
}

// pass D: per-bucket two-pass counting sort, no staging buffer
__global__ __launch_bounds__(512) void k_sort(
        const unsigned* __restrict__ pairs, const int* __restrict__ btotal,
        const int* __restrict__ bbase, int* __restrict__ esrc,
        int* __restrict__ rowp, float* __restrict__ dinv) {
    __shared__ int lcnt[NPB];
    __shared__ int lscan[NPB];
    __shared__ int lcur[NPB];
    int b = blockIdx.x, t = threadIdx.x;
    int nb = btotal[b];
    int base = bbase[b];
    lcnt[t] = 0;
    __syncthreads();
    for (int i = t; i < nb; i += 512) atomicAdd(&lcnt[pairs[base + i] >> 17], 1);
    __syncthreads();
    lscan[t] = lcnt[t];
    __syncthreads();
    for (int off = 1; off < NPB; off <<= 1) {
        int add = (t >= off) ? lscan[t - off] : 0;
        __syncthreads();
        lscan[t] += add;
        __syncthreads();
    }
    lcur[t] = lscan[t] - lcnt[t];
    __syncthreads();
    for (int i = t; i < nb; i += 512) {
        unsigned u = pairs[base + i];
        int d = u >> 17;
        int p = atomicAdd(&lcur[d], 1);
        esrc[base + p] = (int)(u & 0x1FFFFu);
    }
    int node = b * NPB + t;
    if (node < N_NODES) {
        rowp[node] = base + lscan[t] - lcnt[t];
        dinv[node] = rsqrtf((float)lcnt[t] + 1.0f);  // in-degree + self-loop
    }
}

// ---------------- weight folding ----------------
//   Wpack[64][96] = [W3@Wm1 | W3@Wp1],  bpack[96] = [b3@Wm1+bm1 | b3@Wp1+bp1]
//   Wcg[64][64]   = W3@Wg,              bcg[64]   = b3@Wg + bg
__global__ __launch_bounds__(256) void k_fold(
        const float* __restrict__ W3, const float* __restrict__ b3,
        const float* __restrict__ Wm1, const float* __restrict__ bm1,
        const float* __restrict__ Wp1, const float* __restrict__ bp1,
        const float* __restrict__ Wg, const float* __restrict__ bg,
        float* __restrict__ Wpack, float* __restrict__ bpack,
        float* __restrict__ Wcg, float* __restrict__ bcg) {
    int tid = blockIdx.x * 256 + threadIdx.x;
    if (tid < 6144) {                       // Wpack
        int k = tid / 96, c = tid % 96;
        float s = 0.f;
        if (c < 64) {
#pragma unroll 16
            for (int j = 0; j < 64; ++j) s += W3[k * 64 + j] * Wm1[j * 64 + c];
        } else {
            int cc = c - 64;
#pragma unroll 16
            for (int j = 0; j < 64; ++j) s += W3[k * 64 + j] * Wp1[j * 32 + cc];
        }
        Wpack[tid] = s;
    } else if (tid < 10240) {               // Wcg
        int t2 = tid - 6144;
        int k = t2 / 64, c = t2 % 64;
        float s = 0.f;
#pragma unroll 16
        for (int j = 0; j < 64; ++j) s += W3[k * 64 + j] * Wg[j * 64 + c];
        Wcg[t2] = s;
    } else if (tid < 10336) {               // bpack
        int c = tid - 10240;
        float s;
        if (c < 64) {
            s = bm1[c];
            for (int j = 0; j < 64; ++j) s += b3[j] * Wm1[j * 64 + c];
        } else {
            int cc = c - 64;
            s = bp1[cc];
            for (int j = 0; j < 64; ++j) s += b3[j] * Wp1[j * 32 + cc];
        }
        bpack[c] = s;
    } else if (tid < 10400) {               // bcg
        int c = tid - 10336;
        float s = bg[c];
        for (int j = 0; j < 64; ++j) s += b3[j] * Wg[j * 64 + c];
        bcg[c] = s;
    }
}

// ---------------- prepack: xsh[n][k] = fp16(x[n][k] * dinv[n]) ----------------
__global__ __launch_bounds__(256) void k_prepack(
        const float* __restrict__ x, const float* __restrict__ dinv,
        __half* __restrict__ xsh) {
    int n = blockIdx.x * 256 + threadIdx.x;
    if (n >= N_NODES) return;
    float dv = dinv[n];
    const float4* xr = (const float4*)(x + (size_t)n * 8);
    float4 a = xr[0], b = xr[1];
    __half2 h0 = __halves2half2(__float2half_rn(a.x * dv), __float2half_rn(a.y * dv));
    __half2 h1 = __halves2half2(__float2half_rn(a.z * dv), __float2half_rn(a.w * dv));
    __half2 h2 = __halves2half2(__float2half_rn(b.x * dv), __float2half_rn(b.y * dv));
    __half2 h3 = __halves2half2(__float2half_rn(b.z * dv), __float2half_rn(b.w * dv));
    __half2* o = (__half2*)(xsh + (size_t)n * 8);
    o[0] = h0; o[1] = h1; o[2] = h2; o[3] = h3;
}

// ---------------- fused layer 1: agg8 (fp16 prescaled) + transform 8->64 ----------
__global__ __launch_bounds__(256) void k_agg8t(
        const __half* __restrict__ xsh, const float* __restrict__ dinv,
        const int* __restrict__ rp, const int* __restrict__ esrc,
        const float* __restrict__ W1, const float* __restrict__ b1,
        __half* __restrict__ Bout) {
    int gid = (blockIdx.x * 256 + threadIdx.x) >> 5;  // node
    int l = threadIdx.x & 31;
    if (gid >= N_NODES) return;
    int beg = rp[gid], end = rp[gid + 1];
    float a[8];
#pragma unroll
    for (int i = 0; i < 8; ++i) a[i] = 0.f;
    for (int e = beg + l; e < end; e += 32) {
        int s = esrc[e];
        uint4 v = *(const uint4*)(xsh + (size_t)s * 8);
        const __half2* h = (const __half2*)&v;
#pragma unroll
        for (int i = 0; i < 4; ++i) {
            float2 f = __half22float2(h[i]);
            a[2 * i] += f.x; a[2 * i + 1] += f.y;
        }
    }
#pragma unroll
    for (int off = 1; off < 32; off <<= 1) {
#pragma unroll
        for (int i = 0; i < 8; ++i) a[i] += __shfl_xor(a[i], off);
    }
    float dvw = dinv[gid];
    uint4 sv = *(const uint4*)(xsh + (size_t)gid * 8);
    const __half2* sh = (const __half2*)&sv;
    float y[8];
#pragma unroll
    for (int i = 0; i < 4; ++i) {
        float2 fs = __half22float2(sh[i]);
        y[2 * i]     = dvw * (a[2 * i] + fs.x);
        y[2 * i + 1] = dvw * (a[2 * i + 1] + fs.y);
    }
    float acc0 = b1[l], acc1 = b1[l + 32];
#pragma unroll
    for (int k = 0; k < 8; ++k) {
        acc0 += y[k] * W1[k * 64 + l];
        acc1 += y[k] * W1[k * 64 + l + 32];
    }
    Bout[(size_t)gid * 64 + l]      = __float2half_rn(fmaxf(acc0, 0.f) * dvw);
    Bout[(size_t)gid * 64 + l + 32] = __float2half_rn(fmaxf(acc1, 0.f) * dvw);
}

// ---------------- 64-feature aggregate, fp16 operand, 8-slot wide-load form ----------
__global__ __launch_bounds__(256) void k_agg64h(
        const __half* __restrict__ B, float* __restrict__ Y,
        const float* __restrict__ dinv, const int* __restrict__ rp,
        const int* __restrict__ esrc) {
    int wid = (blockIdx.x * 256 + threadIdx.x) >> 6;
    int lane = threadIdx.x & 63;
    if (wid >= N_NODES) return;
    int beg = rp[wid], end = rp[wid + 1];
    int g = lane >> 3;          // edge slot 0..7
    int fl = (lane & 7) << 3;   // half-index base (8 halfs per lane)
    float a0[8], a1[8];
#pragma unroll
    for (int i = 0; i < 8; ++i) { a0[i] = 0.f; a1[i] = 0.f; }
    int e = beg + g;
    for (; e + 8 < end; e += 16) {
        int s0 = esrc[e];
        int s1 = esrc[e + 8];
        uint4 v0 = *(const uint4*)(B + (size_t)s0 * 64 + fl);
        uint4 v1 = *(const uint4*)(B + (size_t)s1 * 64 + fl);
        const __half2* h0 = (const __half2*)&v0;
        const __half2* h1 = (const __half2*)&v1;
#pragma unroll
        for (int i = 0; i < 4; ++i) {
            float2 f0 = __half22float2(h0[i]);
            float2 f1 = __half22float2(h1[i]);
            a0[2 * i] += f0.x; a0[2 * i + 1] += f0.y;
            a1[2 * i] += f1.x; a1[2 * i + 1] += f1.y;
        }
    }
    if (e < end) {
        int s0 = esrc[e];
        uint4 v0 = *(const uint4*)(B + (size_t)s0 * 64 + fl);
        const __half2* h0 = (const __half2*)&v0;
#pragma unroll
        for (int i = 0; i < 4; ++i) {
            float2 f0 = __half22float2(h0[i]);
            a0[2 * i] += f0.x; a0[2 * i + 1] += f0.y;
        }
    }
#pragma unroll
    for (int i = 0; i < 8; ++i) a0[i] += a1[i];
#pragma unroll
    for (int off = 8; off <= 32; off <<= 1) {
#pragma unroll
        for (int i = 0; i < 8; ++i) a0[i] += __shfl_xor(a0[i], off);
    }
    if (lane < 8) {
        uint4 sv = *(const uint4*)(B + (size_t)wid * 64 + fl);
        const __half2* sh = (const __half2*)&sv;
        float dv = dinv[wid];
        float r[8];
#pragma unroll
        for (int i = 0; i < 4; ++i) {
            float2 fs = __half22float2(sh[i]);
            r[2 * i]     = dv * (a0[2 * i] + fs.x);
            r[2 * i + 1] = dv * (a0[2 * i + 1] + fs.y);
        }
        float4 w0 = {r[0], r[1], r[2], r[3]};
        float4 w1 = {r[4], r[5], r[6], r[7]};
        float* yo = Y + (size_t)wid * 64 + fl;
        *(float4*)(yo) = w0;
        *(float4*)(yo + 4) = w1;
    }
}

// register-tiled GEMM (LDS-staged): out = relu(A@W + b)*dinv, fp16 out
__global__ __launch_bounds__(256) void k_gemm64(
        const float* __restrict__ A, const float* __restrict__ W,
        const float* __restrict__ bias, const float* __restrict__ dinv,
        __half* __restrict__ out16) {
    __shared__ float Al[128 * 64];
    __shared__ float Wl[64 * 64];
    int tid = threadIdx.x;
    int base = blockIdx.x * 128;

    for (int idx = tid; idx < 128 * 16; idx += 256) {
        int r = idx >> 4, c4 = idx & 15;
        float4 v = {0.f, 0.f, 0.f, 0.f};
        if (base + r < N_NODES)
            v = *(const float4*)(A + (size_t)(base + r) * 64 + c4 * 4);
        *(float4*)(Al + r * 64 + c4 * 4) = v;
    }
    for (int idx = tid; idx < 64 * 16; idx += 256) {
        int r = idx >> 4, c4 = idx & 15;
        *(float4*)(Wl + r * 64 + c4 * 4) = *(const float4*)(W + r * 64 + c4 * 4);
    }
    __syncthreads();

    int tc = tid & 15;
    int tr = tid >> 4;   // 0..15

    float acc[8][4];
#pragma unroll
    for (int i = 0; i < 8; ++i)
#pragma unroll
        for (int c = 0; c < 4; ++c) acc[i][c] = 0.f;

    for (int kb = 0; kb < 16; ++kb) {
        float w0[4], w1[4], w2[4], w3[4];
        {
            const float* wp = Wl + (kb * 4) * 64 + tc * 4;
            float4 a = *(const float4*)(wp);
            float4 b = *(const float4*)(wp + 64);
            float4 c = *(const float4*)(wp + 128);
            float4 d = *(const float4*)(wp + 192);
            w0[0] = a.x; w0[1] = a.y; w0[2] = a.z; w0[3] = a.w;
            w1[0] = b.x; w1[1] = b.y; w1[2] = b.z; w1[3] = b.w;
            w2[0] = c.x; w2[1] = c.y; w2[2] = c.z; w2[3] = c.w;
            w3[0] = d.x; w3[1] = d.y; w3[2] = d.z; w3[3] = d.w;
        }
#pragma unroll
        for (int i = 0; i < 8; ++i) {
            float4 af = *(const float4*)(Al + (tr * 8 + i) * 64 + kb * 4);
#pragma unroll
            for (int c = 0; c < 4; ++c)
                acc[i][c] += af.x * w0[c] + af.y * w1[c] + af.z * w2[c] + af.w * w3[c];
        }
    }

    float4 bv = *(const float4*)(bias + tc * 4);
#pragma unroll
    for (int i = 0; i < 8; ++i) {
        int r = base + tr * 8 + i;
        if (r < N_NODES) {
            float dv = dinv[r];
            float o0 = fmaxf(acc[i][0] + bv.x, 0.f) * dv;
            float o1 = fmaxf(acc[i][1] + bv.y, 0.f) * dv;
            float o2 = fmaxf(acc[i][2] + bv.z, 0.f) * dv;
            float o3 = fmaxf(acc[i][3] + bv.w, 0.f) * dv;
            __half2 h01 = __halves2half2(__float2half_rn(o0), __float2half_rn(o1));
            __half2 h23 = __halves2half2(__float2half_rn(o2), __float2half_rn(o3));
            __half2* dst = (__half2*)(out16 + (size_t)r * 64 + tc * 4);
            dst[0] = h01; dst[1] = h23;
        }
    }
}

// ---------------- thread-per-node fused head (rule-#20-safe: FULL unroll) ----------
// All y[] accesses compile-time-constant -> registers, no scratch.
__global__ __launch_bounds__(256) void k_headreg(
        const float* __restrict__ Y, const float* __restrict__ Wpack,
        const float* __restrict__ bpack,
        const float* __restrict__ Wm2, const float* __restrict__ bm2,
        const float* __restrict__ Wp2, const float* __restrict__ bp2,
        float* __restrict__ out_m, float* __restrict__ out_p) {
    int n = blockIdx.x * 256 + threadIdx.x;
    if (n >= N_NODES) return;
    float y[64];
    const float4* yr = (const float4*)(Y + (size_t)n * 64);
#pragma unroll
    for (int i = 0; i < 16; ++i) {
        float4 v = yr[i];
        y[4 * i] = v.x; y[4 * i + 1] = v.y; y[4 * i + 2] = v.z; y[4 * i + 3] = v.w;
    }
    float om[9];
#pragma unroll
    for (int j = 0; j < 9; ++j) om[j] = bm2[j];
    float op = bp2[0];
    for (int f = 0; f < 96; ++f) {
        float m = bpack[f];
        const float* wc = Wpack + f;
#pragma unroll
        for (int k = 0; k < 64; ++k) m += y[k] * wc[k * 96];
        m = fmaxf(m, 0.f);
        if (f < 64) {
#pragma unroll
            for (int j = 0; j < 9; ++j) om[j] += m * Wm2[f * 9 + j];
        } else {
            op += m * Wp2[f - 64];
        }
    }
#pragma unroll
    for (int j = 0; j < 9; ++j) out_m[(size_t)n * 9 + j] = om[j];
    out_p[n] = op;
}

// ---------------- fused per-graph head: pool + xglobal + heuristic ----------------
__global__ __launch_bounds__(256) void k_graphhead(
        const float* __restrict__ A, const int* __restrict__ batch,
        const float* __restrict__ Wcg, const float* __restrict__ bcg,
        const float* __restrict__ Wh1, const float* __restrict__ bh1,
        const float* __restrict__ Wh2, const float* __restrict__ bh2,
        float* __restrict__ out_h) {
    __shared__ float l[256];
    __shared__ float xgp[64];
    __shared__ float xg[64];
    int gph = blockIdx.x;
    int t = threadIdx.x;
    int lo = 0, hi = N_NODES;
    int target = (t & 1) ? gph + 1 : gph;
    while (lo < hi) {
        int mid = (lo + hi) >> 1;
        if (batch[mid] < target) lo = mid + 1; else hi = mid;
    }
    __shared__ int bounds[2];
    if (t < 2) bounds[t] = lo;
    __syncthreads();
    int beg = bounds[0], end = bounds[1];

    int lane = t & 63, grp = t >> 6;
    float acc = 0.f;
    for (int r = beg + grp; r < end; r += 4) acc += A[(size_t)r * 64 + lane];
    l[t] = acc;
    __syncthreads();
    if (t < 64) {
        float s = l[t] + l[t + 64] + l[t + 128] + l[t + 192];
        xgp[t] = s / fmaxf((float)(end - beg), 1.f);
    }
    __syncthreads();
    {
        int c = t & 63, q = t >> 6;
        float p = 0.f;
#pragma unroll
        for (int k = 0; k < 16; ++k)
            p += xgp[q * 16 + k] * Wcg[(q * 16 + k) * 64 + c];
        l[t] = p;
        __syncthreads();
        if (t < 64)
            xg[t] = fmaxf(l[t] + l[t + 64] + l[t + 128] + l[t + 192] + bcg[t], 0.f);
    }
    __syncthreads();
    if (t < 32) {
        float hj = bh1[t];
#pragma unroll 16
        for (int k = 0; k < 64; ++k) hj += xg[k] * Wh1[k * 32 + t];
        float q = fmaxf(hj, 0.f) * Wh2[t];
#pragma unroll
        for (int off = 16; off; off >>= 1) q += __shfl_xor(q, off);
        if (t == 0) out_h[gph] = q + bh2[0];
    }
}

// ---------------- launch ----------------

extern "C" void kernel_launch(void* const* d_in, const int* in_sizes, int n_in,
                              void* d_out, int out_size, void* d_ws, size_t ws_size,
                              hipStream_t stream) {
    const float* x    = (const float*)d_in[0];
    const int*   ei   = (const int*)d_in[1];
    const int*   batch= (const int*)d_in[2];
    const float* W1   = (const float*)d_in[3];
    const float* b1   = (const float*)d_in[4];
    const float* W2   = (const float*)d_in[5];
    const float* b2   = (const float*)d_in[6];
    const float* W3   = (const float*)d_in[7];
    const float* b3   = (const float*)d_in[8];
    const float* Wg   = (const float*)d_in[9];
    const float* bg   = (const float*)d_in[10];
    const float* Wh1  = (const float*)d_in[11];
    const float* bh1  = (const float*)d_in[12];
    const float* Wh2  = (const float*)d_in[13];
    const float* bh2  = (const float*)d_in[14];
    const float* Wm1  = (const float*)d_in[15];
    const float* bm1  = (const float*)d_in[16];
    const float* Wm2  = (const float*)d_in[17];
    const float* bm2  = (const float*)d_in[18];
    const float* Wp1  = (const float*)d_in[19];
    const float* bp1  = (const float*)d_in[20];
    const float* Wp2  = (const float*)d_in[21];
    const float* bp2  = (const float*)d_in[22];

    const int* e_src = ei;
    const int* e_dst = ei + N_EDGES;

    char* ws = (char*)d_ws;
    size_t off = 0;
    auto alloc = [&](size_t bytes) {
        void* p = ws + off;
        off += (bytes + 255) & ~(size_t)255;
        return p;
    };
    float* bufA   = (float*)alloc(N_NODES * 64 * sizeof(float));   // 25.6 MB
    float* bufB   = (float*)alloc(N_NODES * 64 * sizeof(float));   // 25.6 MB
    float* dinv   = (float*)alloc(N_NODES * sizeof(float));
    int*   rowp   = (int*)  alloc((N_NODES + 1) * sizeof(int));
    int*   esrc   = (int*)  alloc(N_EDGES * sizeof(int));          // 12.8 MB
    int*   hist   = (int*)  alloc((size_t)NBUCK * NPBLK * sizeof(int)); // 306 KB
    int*   btotal = (int*)  alloc(NBUCK * sizeof(int));
    int*   bbase  = (int*)  alloc(NBUCK * sizeof(int));
    __half* xsh   = (__half*)alloc(N_NODES * 8 * sizeof(__half));  // 1.6 MB
    float* Wpack  = (float*)alloc(64 * 96 * sizeof(float));
    float* bpack  = (float*)alloc(96 * sizeof(float));
    float* Wcg    = (float*)alloc(64 * 64 * sizeof(float));
    float* bcg    = (float*)alloc(64 * sizeof(float));
    // aliases:
    //   pairs (12.8 MB) in bufA[0..) — dead after k_sort, before bufA first written (y2)
    //   B2h (fp16) = bufB[0 .. 3.2M floats); B3h (fp16) = bufB[3.2M .. 6.4M floats)
    //   y2 = bufA (fp32), y3 = bufA (fp32)
    unsigned* pairs = (unsigned*)bufA;
    __half* B2h = (__half*)bufB;
    __half* B3h = (__half*)(bufB + 3200000);
    (void)ws_size; (void)n_in; (void)in_sizes; (void)out_size;

    float* out_h = (float*)d_out;                // [256]
    float* out_m = (float*)d_out + 256;          // [100000*9]
    float* out_p = (float*)d_out + 256 + 900000; // [100000]

    const int TB = 256;
    dim3 blkWave((N_NODES * 64 + TB - 1) / TB);   // one wave per node
    dim3 blkHalf((N_NODES * 32 + TB - 1) / TB);   // 32 lanes per node
    const int NT = 782;                           // ceil(100000/128) GEMM tiles

    // CSR build — atomic-free 3-pass partition + per-bucket two-pass sort
    k_hist<<<NPBLK, TB, 0, stream>>>(e_dst, hist);
    k_scan_rows<<<NBUCK, 512, 0, stream>>>(hist, btotal);
    k_scan_base<<<1, 256, 0, stream>>>(btotal, bbase, rowp + N_NODES);
    k_scatter<<<NPBLK, TB, 0, stream>>>(e_src, e_dst, hist, bbase, pairs);
    k_sort<<<NBUCK, 512, 0, stream>>>(pairs, btotal, bbase, esrc, rowp, dinv);

    // fold W3 into head/global weights (tiny)
    k_fold<<<41, TB, 0, stream>>>(W3, b3, Wm1, bm1, Wp1, bp1, Wg, bg,
                                  Wpack, bpack, Wcg, bcg);

    // layer 1: prepack + fused agg8 + transform -> B2' (fp16)
    k_prepack<<<(N_NODES + TB - 1) / TB, TB, 0, stream>>>(x, dinv, xsh);
    k_agg8t<<<blkHalf, TB, 0, stream>>>(xsh, dinv, rowp, esrc, W1, b1, B2h);
    // layer 2: fp16 gather -> y2 (fp32, bufA); GEMM -> B3' (fp16)
    k_agg64h<<<blkWave, TB, 0, stream>>>(B2h, bufA, dinv, rowp, esrc);
    k_gemm64<<<NT, 256, 0, stream>>>(bufA, W2, b2, dinv, B3h);
    // layer 3: fp16 gather -> y3 (fp32, bufA; y2 dead)
    k_agg64h<<<blkWave, TB, 0, stream>>>(B3h, bufA, dinv, rowp, esrc);

    // node heads: thread-per-node register kernel (M/P1 never materialized)
    k_headreg<<<(N_NODES + TB - 1) / TB, TB, 0, stream>>>(
        bufA, Wpack, bpack, Wm2, bm2, Wp2, bp2, out_m, out_p);

    // fused per-graph head (y3 = bufA, folded Wcg/bcg)
    k_graphhead<<<N_GRAPHS, TB, 0, stream>>>(bufA, batch, Wcg, bcg,
                                             Wh1, bh1, Wh2, bh2, out_h);
}

// Round 20
// 333.753 us; speedup vs baseline: 1.8560x; 1.0401x over previous
//
#include <hip/hip_runtime.h>
#include <hip/hip_fp16.h>

#define N_NODES 100000
#define N_EDGES 3200000
#define N_GRAPHS 256
#define HID 64

// atomic-free bucketed CSR build — 512 nodes/bucket, write-contiguity optimized
#define BSHIFT 9                 // 512 nodes per bucket
#define NPB 512                  // nodes per bucket
#define NBUCK 196                // ceil(100000/512)
#define PCHUNK 8192              // edges per partition block (~42 entries/bucket/block)
#define NPBLK 391                // ceil(3200000/8192)

// pass A: per-block private LDS histogram; hist layout [block][bucket] (coalesced)
__global__ __launch_bounds__(256) void k_hist(
        const int* __restrict__ dst, int* __restrict__ hist) {
    __shared__ int h[NBUCK];
    int t = threadIdx.x;
    for (int j = t; j < NBUCK; j += 256) h[j] = 0;
    __syncthreads();
    int base = blockIdx.x * PCHUNK;
    int end = min(base + PCHUNK, N_EDGES);
    for (int i = base + t; i < end; i += 256)
        atomicAdd(&h[dst[i] >> BSHIFT], 1);
    __syncthreads();
    for (int j = t; j < NBUCK; j += 256)
        hist[(size_t)blockIdx.x * NBUCK + j] = h[j];
}

// pass B1: per-bucket exclusive scan over NPBLK block counts (NPBLK=391 <= 512)
__global__ __launch_bounds__(512) void k_scan_rows(
        int* __restrict__ hist, int* __restrict__ btotal) {
    __shared__ int s[512];
    int b = blockIdx.x, t = threadIdx.x;
    int v = (t < NPBLK) ? hist[(size_t)t * NBUCK + b] : 0;
    s[t] = v;
    __syncthreads();
    for (int off = 1; off < 512; off <<= 1) {
        int add = (t >= off) ? s[t - off] : 0;
        __syncthreads();
        s[t] += add;
        __syncthreads();
    }
    if (t < NPBLK) hist[(size_t)t * NBUCK + b] = s[t] - v;  // exclusive
    if (t == 511) btotal[b] = s[511];
}

// pass B2: exclusive scan over NBUCK bucket totals (single block)
__global__ __launch_bounds__(256) void k_scan_base(
        const int* __restrict__ btotal, int* __restrict__ bbase,
        int* __restrict__ rowp_last) {
    __shared__ int s[256];
    int t = threadIdx.x;
    int v = (t < NBUCK) ? btotal[t] : 0;
    s[t] = v;
    __syncthreads();
    for (int off = 1; off < 256; off <<= 1) {
        int add = (t >= off) ? s[t - off] : 0;
        __syncthreads();
        s[t] += add;
        __syncthreads();
    }
    if (t < NBUCK) bbase[t] = s[t] - v;
    if (t == NBUCK - 1) rowp_last[0] = s[t];
}

// pass C: scatter packed pairs (src | (d&511)<<17) using exact per-(block,bucket)
// offsets (LDS cursors). ~42 consecutive entries per bucket per block.
__global__ __launch_bounds__(256) void k_scatter(
        const int* __restrict__ src, const int* __restrict__ dst,
        const int* __restrict__ hist, const int* __restrict__ bbase,
        unsigned* __restrict__ pairs) {
    __shared__ int cur[NBUCK];
    int t = threadIdx.x;
    for (int j = t; j < NBUCK; j += 256)
        cur[j] = bbase[j] + hist[(size_t)blockIdx.x * NBUCK + j];
    __syncthreads();
    int base = blockIdx.x * PCHUNK;
    int end = min(base + PCHUNK, N_EDGES);
    for (int i = base + t; i < end; i += 256) {
        int d = dst[i], s = src[i];
        int b = d >> BSHIFT;
        int pos = atomicAdd(&cur[b], 1);
        pairs[pos] = (unsigned)s | ((unsigned)(d & (NPB - 1)) << 17);
    }
}

// pass D: per-bucket two-pass counting sort, no staging buffer
__global__ __launch_bounds__(512) void k_sort(
        const unsigned* __restrict__ pairs, const int* __restrict__ btotal,
        const int* __restrict__ bbase, int* __restrict__ esrc,
        int* __restrict__ rowp, float* __restrict__ dinv) {
    __shared__ int lcnt[NPB];
    __shared__ int lscan[NPB];
    __shared__ int lcur[NPB];
    int b = blockIdx.x, t = threadIdx.x;
    int nb = btotal[b];
    int base = bbase[b];
    lcnt[t] = 0;
    __syncthreads();
    for (int i = t; i < nb; i += 512) atomicAdd(&lcnt[pairs[base + i] >> 17], 1);
    __syncthreads();
    lscan[t] = lcnt[t];
    __syncthreads();
    for (int off = 1; off < NPB; off <<= 1) {
        int add = (t >= off) ? lscan[t - off] : 0;
        __syncthreads();
        lscan[t] += add;
        __syncthreads();
    }
    lcur[t] = lscan[t] - lcnt[t];
    __syncthreads();
    for (int i = t; i < nb; i += 512) {
        unsigned u = pairs[base + i];
        int d = u >> 17;
        int p = atomicAdd(&lcur[d], 1);
        esrc[base + p] = (int)(u & 0x1FFFFu);
    }
    int node = b * NPB + t;
    if (node < N_NODES) {
        rowp[node] = base + lscan[t] - lcnt[t];
        dinv[node] = rsqrtf((float)lcnt[t] + 1.0f);  // in-degree + self-loop
    }
}

// ---------------- weight folding ----------------
//   Wpack[64][96] = [W3@Wm1 | W3@Wp1],  bpack[96] = [b3@Wm1+bm1 | b3@Wp1+bp1]
//   Wcg[64][64]   = W3@Wg,              bcg[64]   = b3@Wg + bg
__global__ __launch_bounds__(256) void k_fold(
        const float* __restrict__ W3, const float* __restrict__ b3,
        const float* __restrict__ Wm1, const float* __restrict__ bm1,
        const float* __restrict__ Wp1, const float* __restrict__ bp1,
        const float* __restrict__ Wg, const float* __restrict__ bg,
        float* __restrict__ Wpack, float* __restrict__ bpack,
        float* __restrict__ Wcg, float* __restrict__ bcg) {
    int tid = blockIdx.x * 256 + threadIdx.x;
    if (tid < 6144) {                       // Wpack
        int k = tid / 96, c = tid % 96;
        float s = 0.f;
        if (c < 64) {
#pragma unroll 16
            for (int j = 0; j < 64; ++j) s += W3[k * 64 + j] * Wm1[j * 64 + c];
        } else {
            int cc = c - 64;
#pragma unroll 16
            for (int j = 0; j < 64; ++j) s += W3[k * 64 + j] * Wp1[j * 32 + cc];
        }
        Wpack[tid] = s;
    } else if (tid < 10240) {               // Wcg
        int t2 = tid - 6144;
        int k = t2 / 64, c = t2 % 64;
        float s = 0.f;
#pragma unroll 16
        for (int j = 0; j < 64; ++j) s += W3[k * 64 + j] * Wg[j * 64 + c];
        Wcg[t2] = s;
    } else if (tid < 10336) {               // bpack
        int c = tid - 10240;
        float s;
        if (c < 64) {
            s = bm1[c];
            for (int j = 0; j < 64; ++j) s += b3[j] * Wm1[j * 64 + c];
        } else {
            int cc = c - 64;
            s = bp1[cc];
            for (int j = 0; j < 64; ++j) s += b3[j] * Wp1[j * 32 + cc];
        }
        bpack[c] = s;
    } else if (tid < 10400) {               // bcg
        int c = tid - 10336;
        float s = bg[c];
        for (int j = 0; j < 64; ++j) s += b3[j] * Wg[j * 64 + c];
        bcg[c] = s;
    }
}

// ---------------- prepack: xsh[n][k] = fp16(x[n][k] * dinv[n]) ----------------
__global__ __launch_bounds__(256) void k_prepack(
        const float* __restrict__ x, const float* __restrict__ dinv,
        __half* __restrict__ xsh) {
    int n = blockIdx.x * 256 + threadIdx.x;
    if (n >= N_NODES) return;
    float dv = dinv[n];
    const float4* xr = (const float4*)(x + (size_t)n * 8);
    float4 a = xr[0], b = xr[1];
    __half2 h0 = __halves2half2(__float2half_rn(a.x * dv), __float2half_rn(a.y * dv));
    __half2 h1 = __halves2half2(__float2half_rn(a.z * dv), __float2half_rn(a.w * dv));
    __half2 h2 = __halves2half2(__float2half_rn(b.x * dv), __float2half_rn(b.y * dv));
    __half2 h3 = __halves2half2(__float2half_rn(b.z * dv), __float2half_rn(b.w * dv));
    __half2* o = (__half2*)(xsh + (size_t)n * 8);
    o[0] = h0; o[1] = h1; o[2] = h2; o[3] = h3;
}

// ---------------- fused layer 1: agg8 (fp16 prescaled) + transform 8->64 ----------
__global__ __launch_bounds__(256) void k_agg8t(
        const __half* __restrict__ xsh, const float* __restrict__ dinv,
        const int* __restrict__ rp, const int* __restrict__ esrc,
        const float* __restrict__ W1, const float* __restrict__ b1,
        __half* __restrict__ Bout) {
    int gid = (blockIdx.x * 256 + threadIdx.x) >> 5;  // node
    int l = threadIdx.x & 31;
    if (gid >= N_NODES) return;
    int beg = rp[gid], end = rp[gid + 1];
    float a[8];
#pragma unroll
    for (int i = 0; i < 8; ++i) a[i] = 0.f;
    for (int e = beg + l; e < end; e += 32) {
        int s = esrc[e];
        uint4 v = *(const uint4*)(xsh + (size_t)s * 8);
        const __half2* h = (const __half2*)&v;
#pragma unroll
        for (int i = 0; i < 4; ++i) {
            float2 f = __half22float2(h[i]);
            a[2 * i] += f.x; a[2 * i + 1] += f.y;
        }
    }
#pragma unroll
    for (int off = 1; off < 32; off <<= 1) {
#pragma unroll
        for (int i = 0; i < 8; ++i) a[i] += __shfl_xor(a[i], off);
    }
    float dvw = dinv[gid];
    uint4 sv = *(const uint4*)(xsh + (size_t)gid * 8);
    const __half2* sh = (const __half2*)&sv;
    float y[8];
#pragma unroll
    for (int i = 0; i < 4; ++i) {
        float2 fs = __half22float2(sh[i]);
        y[2 * i]     = dvw * (a[2 * i] + fs.x);
        y[2 * i + 1] = dvw * (a[2 * i + 1] + fs.y);
    }
    float acc0 = b1[l], acc1 = b1[l + 32];
#pragma unroll
    for (int k = 0; k < 8; ++k) {
        acc0 += y[k] * W1[k * 64 + l];
        acc1 += y[k] * W1[k * 64 + l + 32];
    }
    Bout[(size_t)gid * 64 + l]      = __float2half_rn(fmaxf(acc0, 0.f) * dvw);
    Bout[(size_t)gid * 64 + l + 32] = __float2half_rn(fmaxf(acc1, 0.f) * dvw);
}

// ---------------- 64-feature aggregate, fp16 operand, 8-slot wide-load form ----------
__global__ __launch_bounds__(256) void k_agg64h(
        const __half* __restrict__ B, float* __restrict__ Y,
        const float* __restrict__ dinv, const int* __restrict__ rp,
        const int* __restrict__ esrc) {
    int wid = (blockIdx.x * 256 + threadIdx.x) >> 6;
    int lane = threadIdx.x & 63;
    if (wid >= N_NODES) return;
    int beg = rp[wid], end = rp[wid + 1];
    int g = lane >> 3;          // edge slot 0..7
    int fl = (lane & 7) << 3;   // half-index base (8 halfs per lane)
    float a0[8], a1[8];
#pragma unroll
    for (int i = 0; i < 8; ++i) { a0[i] = 0.f; a1[i] = 0.f; }
    int e = beg + g;
    for (; e + 8 < end; e += 16) {
        int s0 = esrc[e];
        int s1 = esrc[e + 8];
        uint4 v0 = *(const uint4*)(B + (size_t)s0 * 64 + fl);
        uint4 v1 = *(const uint4*)(B + (size_t)s1 * 64 + fl);
        const __half2* h0 = (const __half2*)&v0;
        const __half2* h1 = (const __half2*)&v1;
#pragma unroll
        for (int i = 0; i < 4; ++i) {
            float2 f0 = __half22float2(h0[i]);
            float2 f1 = __half22float2(h1[i]);
            a0[2 * i] += f0.x; a0[2 * i + 1] += f0.y;
            a1[2 * i] += f1.x; a1[2 * i + 1] += f1.y;
        }
    }
    if (e < end) {
        int s0 = esrc[e];
        uint4 v0 = *(const uint4*)(B + (size_t)s0 * 64 + fl);
        const __half2* h0 = (const __half2*)&v0;
#pragma unroll
        for (int i = 0; i < 4; ++i) {
            float2 f0 = __half22float2(h0[i]);
            a0[2 * i] += f0.x; a0[2 * i + 1] += f0.y;
        }
    }
#pragma unroll
    for (int i = 0; i < 8; ++i) a0[i] += a1[i];
#pragma unroll
    for (int off = 8; off <= 32; off <<= 1) {
#pragma unroll
        for (int i = 0; i < 8; ++i) a0[i] += __shfl_xor(a0[i], off);
    }
    if (lane < 8) {
        uint4 sv = *(const uint4*)(B + (size_t)wid * 64 + fl);
        const __half2* sh = (const __half2*)&sv;
        float dv = dinv[wid];
        float r[8];
#pragma unroll
        for (int i = 0; i < 4; ++i) {
            float2 fs = __half22float2(sh[i]);
            r[2 * i]     = dv * (a0[2 * i] + fs.x);
            r[2 * i + 1] = dv * (a0[2 * i + 1] + fs.y);
        }
        float4 w0 = {r[0], r[1], r[2], r[3]};
        float4 w1 = {r[4], r[5], r[6], r[7]};
        float* yo = Y + (size_t)wid * 64 + fl;
        *(float4*)(yo) = w0;
        *(float4*)(yo + 4) = w1;
    }
}

// register-tiled GEMM: out[128 x NCOL tile] = act(A[128x64] @ W[64xNCOL] + bias)
// OUTH: write result as fp16. PHEAD: cols 64..95 are P1 -> out_p; cols 0..63 are M
// (kept in LDS) -> out_m in-block.
template <int NCOL, int RELU, int SCALE, int PHEAD, int OUTH>
__global__ __launch_bounds__(NCOL * 4) void k_gemm(
        const float* __restrict__ A, const float* __restrict__ W,
        const float* __restrict__ bias, const float* __restrict__ dinv,
        float* __restrict__ out32, __half* __restrict__ out16,
        const float* __restrict__ Wp2, const float* __restrict__ bp2,
        float* __restrict__ out_p,
        const float* __restrict__ Wm2, const float* __restrict__ bm2,
        float* __restrict__ out_m) {
    __shared__ float Al[128 * 64];
    __shared__ float Wl[64 * NCOL];
    __shared__ float pbuf[PHEAD ? 128 * 8 : 4];
    __shared__ float wm2l[PHEAD ? 64 * 9 : 4];
    __shared__ float bm2l[PHEAD ? 9 : 1];
    const int NTHR = NCOL * 4;
    int tid = threadIdx.x;
    int base = blockIdx.x * 128;

    for (int idx = tid; idx < 128 * 16; idx += NTHR) {
        int r = idx >> 4, c4 = idx & 15;
        float4 v = {0.f, 0.f, 0.f, 0.f};
        if (base + r < N_NODES)
            v = *(const float4*)(A + (size_t)(base + r) * 64 + c4 * 4);
        *(float4*)(Al + r * 64 + c4 * 4) = v;
    }
    for (int idx = tid; idx < 64 * (NCOL / 4); idx += NTHR) {
        int r = idx / (NCOL / 4), c4 = idx % (NCOL / 4);
        *(float4*)(Wl + r * NCOL + c4 * 4) = *(const float4*)(W + r * NCOL + c4 * 4);
    }
    if (PHEAD) {
        for (int i = tid; i < 576; i += NTHR) wm2l[i] = Wm2[i];
        if (tid < 9) bm2l[tid] = bm2[tid];
    }
    __syncthreads();

    int tc = tid % (NCOL / 4);
    int tr = tid / (NCOL / 4);   // 0..15

    float acc[8][4];
#pragma unroll
    for (int i = 0; i < 8; ++i)
#pragma unroll
        for (int c = 0; c < 4; ++c) acc[i][c] = 0.f;

    for (int kb = 0; kb < 16; ++kb) {
        float w0[4], w1[4], w2[4], w3[4];
        {
            const float* wp = Wl + (kb * 4) * NCOL + tc * 4;
            float4 a = *(const float4*)(wp);
            float4 b = *(const float4*)(wp + NCOL);
            float4 c = *(const float4*)(wp + 2 * NCOL);
            float4 d = *(const float4*)(wp + 3 * NCOL);
            w0[0] = a.x; w0[1] = a.y; w0[2] = a.z; w0[3] = a.w;
            w1[0] = b.x; w1[1] = b.y; w1[2] = b.z; w1[3] = b.w;
            w2[0] = c.x; w2[1] = c.y; w2[2] = c.z; w2[3] = c.w;
            w3[0] = d.x; w3[1] = d.y; w3[2] = d.z; w3[3] = d.w;
        }
#pragma unroll
        for (int i = 0; i < 8; ++i) {
            float4 af = *(const float4*)(Al + (tr * 8 + i) * 64 + kb * 4);
#pragma unroll
            for (int c = 0; c < 4; ++c)
                acc[i][c] += af.x * w0[c] + af.y * w1[c] + af.z * w2[c] + af.w * w3[c];
        }
    }

    if (PHEAD) __syncthreads();  // all Al reads done before M overwrites it

    float4 bv = *(const float4*)(bias + tc * 4);
    float wp2l[4] = {0.f, 0.f, 0.f, 0.f};
    if (PHEAD && tc >= 16) {
        float4 wv = *(const float4*)(Wp2 + (tc - 16) * 4);
        wp2l[0] = wv.x; wp2l[1] = wv.y; wp2l[2] = wv.z; wp2l[3] = wv.w;
    }
#pragma unroll
    for (int i = 0; i < 8; ++i) {
        int lr = tr * 8 + i;
        int r = base + lr;
        bool ok = r < N_NODES;
        float o0 = acc[i][0] + bv.x, o1 = acc[i][1] + bv.y;
        float o2 = acc[i][2] + bv.z, o3 = acc[i][3] + bv.w;
        if (RELU) {
            o0 = fmaxf(o0, 0.f); o1 = fmaxf(o1, 0.f);
            o2 = fmaxf(o2, 0.f); o3 = fmaxf(o3, 0.f);
        }
        if (SCALE) {
            float dv = ok ? dinv[r] : 0.f;
            o0 *= dv; o1 *= dv; o2 *= dv; o3 *= dv;
        }
        if (PHEAD) {
            if (tc >= 16) {
                pbuf[lr * 8 + (tc - 16)] =
                    o0 * wp2l[0] + o1 * wp2l[1] + o2 * wp2l[2] + o3 * wp2l[3];
            } else {
                float4 st = {o0, o1, o2, o3};
                *(float4*)(Al + lr * 64 + tc * 4) = st;  // M tile into LDS
            }
        } else if (ok) {
            if (OUTH) {
                __half2 h01 = __halves2half2(__float2half_rn(o0), __float2half_rn(o1));
                __half2 h23 = __halves2half2(__float2half_rn(o2), __float2half_rn(o3));
                __half2* dst = (__half2*)(out16 + (size_t)r * 64 + tc * 4);
                dst[0] = h01; dst[1] = h23;
            } else {
                float4 st = {o0, o1, o2, o3};
                *(float4*)(out32 + (size_t)r * 64 + tc * 4) = st;
            }
        }
    }
    if (PHEAD) {
        __syncthreads();
        for (int o = tid; o < 128 * 9; o += NTHR) {
            int rr = o / 9, j = o - rr * 9;
            int node = base + rr;
            if (node < N_NODES) {
                float s = bm2l[j];
#pragma unroll 16
                for (int k = 0; k < 64; ++k) s += Al[rr * 64 + k] * wm2l[k * 9 + j];
                out_m[(size_t)node * 9 + j] = s;
            }
        }
        if (tid < 128) {
            int r = base + tid;
            if (r < N_NODES) {
                float s = 0.f;
#pragma unroll
                for (int j = 0; j < 8; ++j) s += pbuf[tid * 8 + j];
                out_p[r] = s + bp2[0];
            }
        }
    }
}

// ---------------- fused per-graph head: pool + xglobal + heuristic ----------------
__global__ __launch_bounds__(256) void k_graphhead(
        const float* __restrict__ A, const int* __restrict__ batch,
        const float* __restrict__ Wcg, const float* __restrict__ bcg,
        const float* __restrict__ Wh1, const float* __restrict__ bh1,
        const float* __restrict__ Wh2, const float* __restrict__ bh2,
        float* __restrict__ out_h) {
    __shared__ float l[256];
    __shared__ float xgp[64];
    __shared__ float xg[64];
    int gph = blockIdx.x;
    int t = threadIdx.x;
    int lo = 0, hi = N_NODES;
    int target = (t & 1) ? gph + 1 : gph;
    while (lo < hi) {
        int mid = (lo + hi) >> 1;
        if (batch[mid] < target) lo = mid + 1; else hi = mid;
    }
    __shared__ int bounds[2];
    if (t < 2) bounds[t] = lo;
    __syncthreads();
    int beg = bounds[0], end = bounds[1];

    int lane = t & 63, grp = t >> 6;
    float acc = 0.f;
    for (int r = beg + grp; r < end; r += 4) acc += A[(size_t)r * 64 + lane];
    l[t] = acc;
    __syncthreads();
    if (t < 64) {
        float s = l[t] + l[t + 64] + l[t + 128] + l[t + 192];
        xgp[t] = s / fmaxf((float)(end - beg), 1.f);
    }
    __syncthreads();
    {
        int c = t & 63, q = t >> 6;
        float p = 0.f;
#pragma unroll
        for (int k = 0; k < 16; ++k)
            p += xgp[q * 16 + k] * Wcg[(q * 16 + k) * 64 + c];
        l[t] = p;
        __syncthreads();
        if (t < 64)
            xg[t] = fmaxf(l[t] + l[t + 64] + l[t + 128] + l[t + 192] + bcg[t], 0.f);
    }
    __syncthreads();
    if (t < 32) {
        float hj = bh1[t];
#pragma unroll 16
        for (int k = 0; k < 64; ++k) hj += xg[k] * Wh1[k * 32 + t];
        float q = fmaxf(hj, 0.f) * Wh2[t];
#pragma unroll
        for (int off = 16; off; off >>= 1) q += __shfl_xor(q, off);
        if (t == 0) out_h[gph] = q + bh2[0];
    }
}

// ---------------- launch ----------------

extern "C" void kernel_launch(void* const* d_in, const int* in_sizes, int n_in,
                              void* d_out, int out_size, void* d_ws, size_t ws_size,
                              hipStream_t stream) {
    const float* x    = (const float*)d_in[0];
    const int*   ei   = (const int*)d_in[1];
    const int*   batch= (const int*)d_in[2];
    const float* W1   = (const float*)d_in[3];
    const float* b1   = (const float*)d_in[4];
    const float* W2   = (const float*)d_in[5];
    const float* b2   = (const float*)d_in[6];
    const float* W3   = (const float*)d_in[7];
    const float* b3   = (const float*)d_in[8];
    const float* Wg   = (const float*)d_in[9];
    const float* bg   = (const float*)d_in[10];
    const float* Wh1  = (const float*)d_in[11];
    const float* bh1  = (const float*)d_in[12];
    const float* Wh2  = (const float*)d_in[13];
    const float* bh2  = (const float*)d_in[14];
    const float* Wm1  = (const float*)d_in[15];
    const float* bm1  = (const float*)d_in[16];
    const float* Wm2  = (const float*)d_in[17];
    const float* bm2  = (const float*)d_in[18];
    const float* Wp1  = (const float*)d_in[19];
    const float* bp1  = (const float*)d_in[20];
    const float* Wp2  = (const float*)d_in[21];
    const float* bp2  = (const float*)d_in[22];

    const int* e_src = ei;
    const int* e_dst = ei + N_EDGES;

    char* ws = (char*)d_ws;
    size_t off = 0;
    auto alloc = [&](size_t bytes) {
        void* p = ws + off;
        off += (bytes + 255) & ~(size_t)255;
        return p;
    };
    float* bufA   = (float*)alloc(N_NODES * 64 * sizeof(float));   // 25.6 MB
    float* bufB   = (float*)alloc(N_NODES * 64 * sizeof(float));   // 25.6 MB
    float* dinv   = (float*)alloc(N_NODES * sizeof(float));
    int*   rowp   = (int*)  alloc((N_NODES + 1) * sizeof(int));
    int*   esrc   = (int*)  alloc(N_EDGES * sizeof(int));          // 12.8 MB
    int*   hist   = (int*)  alloc((size_t)NBUCK * NPBLK * sizeof(int)); // 306 KB
    int*   btotal = (int*)  alloc(NBUCK * sizeof(int));
    int*   bbase  = (int*)  alloc(NBUCK * sizeof(int));
    __half* xsh   = (__half*)alloc(N_NODES * 8 * sizeof(__half));  // 1.6 MB
    float* Wpack  = (float*)alloc(64 * 96 * sizeof(float));
    float* bpack  = (float*)alloc(96 * sizeof(float));
    float* Wcg    = (float*)alloc(64 * 64 * sizeof(float));
    float* bcg    = (float*)alloc(64 * sizeof(float));
    // aliases:
    //   pairs (12.8 MB) in bufA[0..) — dead after k_sort, before bufA first written (y2)
    //   B2h (fp16) = bufB[0 .. 3.2M floats); B3h (fp16) = bufB[3.2M .. 6.4M floats)
    //   y2 = bufA (fp32), y3 = bufA (fp32)
    unsigned* pairs = (unsigned*)bufA;
    __half* B2h = (__half*)bufB;
    __half* B3h = (__half*)(bufB + 3200000);
    (void)ws_size; (void)n_in; (void)in_sizes; (void)out_size;

    float* out_h = (float*)d_out;                // [256]
    float* out_m = (float*)d_out + 256;          // [100000*9]
    float* out_p = (float*)d_out + 256 + 900000; // [100000]

    const int TB = 256;
    dim3 blkWave((N_NODES * 64 + TB - 1) / TB);   // one wave per node
    dim3 blkHalf((N_NODES * 32 + TB - 1) / TB);   // 32 lanes per node
    const int NT = 782;                           // ceil(100000/128) GEMM tiles

    // CSR build — atomic-free 3-pass partition + per-bucket two-pass sort
    k_hist<<<NPBLK, TB, 0, stream>>>(e_dst, hist);
    k_scan_rows<<<NBUCK, 512, 0, stream>>>(hist, btotal);
    k_scan_base<<<1, 256, 0, stream>>>(btotal, bbase, rowp + N_NODES);
    k_scatter<<<NPBLK, TB, 0, stream>>>(e_src, e_dst, hist, bbase, pairs);
    k_sort<<<NBUCK, 512, 0, stream>>>(pairs, btotal, bbase, esrc, rowp, dinv);

    // fold W3 into head/global weights (tiny)
    k_fold<<<41, TB, 0, stream>>>(W3, b3, Wm1, bm1, Wp1, bp1, Wg, bg,
                                  Wpack, bpack, Wcg, bcg);

    // layer 1: prepack + fused agg8 + transform -> B2' (fp16)
    k_prepack<<<(N_NODES + TB - 1) / TB, TB, 0, stream>>>(x, dinv, xsh);
    k_agg8t<<<blkHalf, TB, 0, stream>>>(xsh, dinv, rowp, esrc, W1, b1, B2h);
    // layer 2: fp16 gather -> y2 (fp32, bufA); GEMM -> B3' (fp16)
    k_agg64h<<<blkWave, TB, 0, stream>>>(B2h, bufA, dinv, rowp, esrc);
    k_gemm<64, 1, 1, 0, 1><<<NT, 256, 0, stream>>>(
        bufA, W2, b2, dinv, nullptr, B3h,
        nullptr, nullptr, nullptr, nullptr, nullptr, nullptr);
    // layer 3: fp16 gather -> y3 (fp32, bufA; y2 dead)
    k_agg64h<<<blkWave, TB, 0, stream>>>(B3h, bufA, dinv, rowp, esrc);

    // heads: [M | P1] GEMM; M stays in LDS -> out_m; P1 -> out_p
    k_gemm<96, 1, 0, 1, 0><<<NT, 384, 0, stream>>>(
        bufA, Wpack, bpack, nullptr, nullptr, nullptr,
        Wp2, bp2, out_p, Wm2, bm2, out_m);

    // fused per-graph head (y3 = bufA, folded Wcg/bcg)
    k_graphhead<<<N_GRAPHS, TB, 0, stream>>>(bufA, batch, Wcg, bcg,
                                             Wh1, bh1, Wh2, bh2, out_h);
}